// Round 21
// baseline (86.971 us; speedup 1.0000x reference)
//
#include <hip/hip_runtime.h>
#include <hip/hip_bf16.h>
#include <cstdint>
#include <cstddef>

// GAU fused pipeline. fp32 I/O; bf16 MFMA internally.
// B=16 C=256 H=W=64 (HW=4096) S=128 O=256. ws: 36 MiB.
// RoPE eliminated algebraically (same-position q.k is rotation-invariant).
// k_fused: 32-position tiles, 34KB LDS -> 3 blocks/CU (TLP to hide W-load latency).

typedef __attribute__((ext_vector_type(8))) short short8;     // 8 bf16 MFMA frag
typedef __attribute__((ext_vector_type(4))) float f32x4;
typedef __attribute__((ext_vector_type(4))) unsigned int uint4v;
typedef __attribute__((ext_vector_type(2))) unsigned int uint2v;

#define DI __device__ __forceinline__

DI float bf2f(unsigned short u){ unsigned int i = ((unsigned int)u)<<16; float f; __builtin_memcpy(&f,&i,4); return f; }
DI unsigned int pk2bf(float lo, float hi){
  float2 f2; f2.x = lo; f2.y = hi;
  __hip_bfloat162 h = __float22bfloat162_rn(f2);
  unsigned int u; __builtin_memcpy(&u, &h, 4); return u;
}

DI void gload16(const void* g, void* l){
  __builtin_amdgcn_global_load_lds((const __attribute__((address_space(1))) void*)g,
                                   (__attribute__((address_space(3))) void*)l, 16, 0, 0);
}

// ---------------- K0: pack weights fp32->bf16 + biases ----------------
// wcat: [nt(5)][ks(4)][k8(8)][n(128)][8]  (o=nt*128+n, c=ks*64+k8*8+j; nt 0-1 gate, 2-3 value, 4 z)
// proj: [oh(2)][ks(4)][k8(8)][o(128)][8]
__global__ __launch_bounds__(256) void k_pack_w(
    const float* __restrict__ gW, const float* __restrict__ vW,
    const float* __restrict__ zW, const float* __restrict__ pW,
    const float* __restrict__ gB, const float* __restrict__ vB,
    const float* __restrict__ zB, const float* __restrict__ pB,
    unsigned short* __restrict__ wcat, unsigned short* __restrict__ proj,
    float* __restrict__ biases){
  int id = blockIdx.x*256 + threadIdx.x;
  if (id < 20480){
    int n=id&127, k8=(id>>7)&7, ks=(id>>10)&3, nt=id>>12;
    int o = nt*128+n, c0 = ks*64+k8*8;
    const float* src = (o<256) ? gW + (size_t)o*256 + c0
                      : (o<512) ? vW + (size_t)(o-256)*256 + c0
                      :           zW + (size_t)(o-512)*256 + c0;
    f32x4 a = *(const f32x4*)src, b = *(const f32x4*)(src+4);
    uint4v ov;
    ov[0] = pk2bf(a[0],a[1]); ov[1] = pk2bf(a[2],a[3]);
    ov[2] = pk2bf(b[0],b[1]); ov[3] = pk2bf(b[2],b[3]);
    *(uint4v*)(wcat + (size_t)id*8) = ov;
  } else if (id < 28672){
    int q = id - 20480;
    int m=q&127, k8=(q>>7)&7, ks=(q>>10)&3, mt=q>>12;
    int o = mt*128+m, c0 = ks*64+k8*8;
    const float* src = pW + (size_t)o*256 + c0;
    f32x4 a = *(const f32x4*)src, b = *(const f32x4*)(src+4);
    uint4v ov;
    ov[0] = pk2bf(a[0],a[1]); ov[1] = pk2bf(a[2],a[3]);
    ov[2] = pk2bf(b[0],b[1]); ov[3] = pk2bf(b[2],b[3]);
    *(uint4v*)(proj + (size_t)q*8) = ov;
  }
  if (id < 640) biases[id] = id<256 ? gB[id] : id<512 ? vB[id-256] : zB[id-512];
  if (id < 256) biases[640+id] = pB[id];
}

// ---------------- K1: per-(b,c) mean / rstd over 4096 ----------------
__global__ __launch_bounds__(256) void k_stats(const float* __restrict__ x, float* __restrict__ stats){
  int bc = blockIdx.x, t = threadIdx.x, lane = t&63, wid = t>>6;
  const f32x4* row = (const f32x4*)(x + (size_t)bc*4096);
  float s=0.f, q=0.f;
  #pragma unroll
  for (int i=0;i<4;i++){
    f32x4 v = row[i*256+t];
    #pragma unroll
    for (int w=0;w<4;w++){ s += v[w]; q += v[w]*v[w]; }
  }
  #pragma unroll
  for (int off=32; off; off>>=1){ s += __shfl_xor(s,off); q += __shfl_xor(q,off); }
  __shared__ float r1[4], r2[4];
  if (lane==0){ r1[wid]=s; r2[wid]=q; }
  __syncthreads();
  if (t==0){
    float S=r1[0]+r1[1]+r1[2]+r1[3], Q=r2[0]+r2[1]+r2[2]+r2[3];
    float mu = S*(1.0f/4096.0f);
    float var = Q*(1.0f/4096.0f) - mu*mu;
    stats[bc*2]   = mu;
    stats[bc*2+1] = rsqrtf(var + 1e-5f);
  }
}

// ---------------- K2: normalize + pack xn (bf16) ----------------
// apack: [b(16)][mt(32)][ks(4)][k8(8)][m(128)][8], elem = xn[b][c=ks*64+k8*8+j][hw=mt*128+m]
__global__ __launch_bounds__(256) void k_xn_pack(const float* __restrict__ x,
    const float* __restrict__ stats, unsigned short* __restrict__ apack){
  size_t id = (size_t)blockIdx.x*256 + threadIdx.x;
  int m=(int)(id&127), k8=(int)(id>>7)&7, ks=(int)(id>>10)&3, mt=(int)(id>>12)&31, b=(int)(id>>17);
  int hw = mt*128+m, c0 = ks*64+k8*8;
  const float* xp = x + ((size_t)(b*256 + c0))*4096 + hw;
  const float* st = stats + (size_t)(b*256+c0)*2;
  uint4v o;
  #pragma unroll
  for (int j=0;j<8;j+=2){
    float v0 = (xp[(size_t)j*4096]     - st[j*2])   * st[j*2+1];
    float v1 = (xp[(size_t)(j+1)*4096] - st[j*2+2]) * st[j*2+3];
    o[j>>1] = pk2bf(v0, v1);
  }
  *(uint4v*)(apack + id*8) = o;
}

// ---------------- K3: z GEMM + fused affine + same-position q.k -> sim ----------------
// Grid 16 x 32 (XCD-swizzled). BK=32, 3 LDS buffers, depth-2 counted vmcnt.
__global__ __launch_bounds__(256,3) void k_zsim(
    const unsigned short* __restrict__ Ap, const unsigned short* __restrict__ Wc,
    const float* __restrict__ biases, const float* __restrict__ gm, const float* __restrict__ bt,
    float* __restrict__ sim){
  __shared__ alignas(16) unsigned short lds[3][2][4096];
  __shared__ float red[2][4][16][2];
  int orig = blockIdx.x;
  int wg = (orig&7)*64 + (orig>>3);            // bijective (512%8==0)
  int b = wg>>5, mt = wg&31;
  const unsigned short* Xt = Ap + (size_t)(b*32+mt)*32768;
  int t = threadIdx.x, lane = t&63;
  int wo = (t>>6)>>1, wm = (t>>6)&1;

  #define STAGEZ(B, cc) do{ \
    _Pragma("unroll") \
    for (int i_=0;i_<2;i_++){ \
      int u_ = i_*256 + t; \
      int k8_ = u_>>7, slot_ = u_&127; \
      gload16(Wc + ((size_t)(16+((cc)>>1))*8 + (((cc)&1)<<2) + k8_)*1024 + (size_t)slot_*8, &lds[B][0][(size_t)u_*8]); \
      gload16(Xt + ((size_t)((cc)*4 + k8_))*1024 + (size_t)slot_*8, &lds[B][1][(size_t)u_*8]); \
    } \
  }while(0)

  f32x4 accg[2][4]={}, accv[2][4]={};

  #define CZ(B) do{ \
    int k8l_ = lane>>4; \
    short8 wgf_[2], wvf_[2], xf_[4]; \
    _Pragma("unroll") for (int ci_=0;ci_<2;ci_++){ \
      int sg_ = wo*32 + ci_*16 + (lane&15); \
      wgf_[ci_] = *(const short8*)&lds[B][0][(size_t)(k8l_*128 + sg_)*8]; \
      wvf_[ci_] = *(const short8*)&lds[B][0][(size_t)(k8l_*128 + 64 + sg_)*8]; } \
    _Pragma("unroll") for (int mj_=0;mj_<4;mj_++) \
      xf_[mj_] = *(const short8*)&lds[B][1][(size_t)(k8l_*128 + wm*64 + mj_*16 + (lane&15))*8]; \
    _Pragma("unroll") for (int ci_=0;ci_<2;ci_++) \
      _Pragma("unroll") for (int mj_=0;mj_<4;mj_++){ \
        accg[ci_][mj_] = __builtin_amdgcn_mfma_f32_16x16x32_bf16(wgf_[ci_], xf_[mj_], accg[ci_][mj_],0,0,0); \
        accv[ci_][mj_] = __builtin_amdgcn_mfma_f32_16x16x32_bf16(wvf_[ci_], xf_[mj_], accv[ci_][mj_],0,0,0); } \
  }while(0)

  STAGEZ(0,0);
  STAGEZ(1,1);
  asm volatile("s_waitcnt vmcnt(4)" ::: "memory");
  __builtin_amdgcn_s_barrier();
  __builtin_amdgcn_sched_barrier(0);
  #pragma unroll
  for (int c=0; c<8; ++c){
    if (c<6) STAGEZ((c+2)%3, c+2);
    CZ(c%3);
    if (c<6)       asm volatile("s_waitcnt vmcnt(4)" ::: "memory");
    else if (c==6) asm volatile("s_waitcnt vmcnt(0)" ::: "memory");
    if (c<7){ __builtin_amdgcn_s_barrier(); __builtin_amdgcn_sched_barrier(0); }
  }

  float part[4] = {0.f,0.f,0.f,0.f};
  #pragma unroll
  for (int ci=0;ci<2;ci++){
    int cq = wo*32 + ci*16 + ((lane>>4)<<2);
    f32x4 bz0 = *(const f32x4*)&biases[512+cq];
    f32x4 bz1 = *(const f32x4*)&biases[512+64+cq];
    f32x4 g0a = *(const f32x4*)&gm[cq],      g1a = *(const f32x4*)&gm[128+cq];
    f32x4 b0a = *(const f32x4*)&bt[cq],      b1a = *(const f32x4*)&bt[128+cq];
    f32x4 g0b = *(const f32x4*)&gm[64+cq],   g1b = *(const f32x4*)&gm[192+cq];
    f32x4 b0b = *(const f32x4*)&bt[64+cq],   b1b = *(const f32x4*)&bt[192+cq];
    #pragma unroll
    for (int mj=0;mj<4;mj++){
      f32x4 z0 = accg[ci][mj] + bz0;
      f32x4 z1 = accv[ci][mj] + bz1;
      f32x4 c0 = (z0*g0a + b0a) * (z0*g1a + b1a);
      f32x4 c1 = (z1*g0b + b0b) * (z1*g1b + b1b);
      part[mj] += c0[0]+c0[1]+c0[2]+c0[3] + c1[0]+c1[1]+c1[2]+c1[3];
    }
  }
  #pragma unroll
  for (int mj=0;mj<4;mj++){
    float rr = part[mj];
    rr += __shfl_xor(rr, 16);
    rr += __shfl_xor(rr, 32);
    if (lane < 16) red[wm][mj][lane][wo] = rr;
  }
  __syncthreads();
  if (t < 128){
    int wmq = t>>6, mjq = (t>>4)&3, lq = t&15;
    float s = red[wmq][mjq][lq][0] + red[wmq][mjq][lq][1];
    sim[(size_t)b*4096 + mt*128 + wmq*64 + mjq*16 + lq] = s * 0.08838834764831845f;
  }
  #undef STAGEZ
  #undef CZ
}

// ---------------- K4: per-batch softmax over 4096 -> A ----------------
__global__ __launch_bounds__(256) void k_softmax(const float* __restrict__ sim, float* __restrict__ A){
  int b = blockIdx.x, t = threadIdx.x, lane = t&63, wid = t>>6;
  const f32x4* s4 = (const f32x4*)(sim + (size_t)b*4096);
  f32x4 v[4];
  float mx = -3.4e38f;
  #pragma unroll
  for (int i=0;i<4;i++){
    v[i] = s4[i*256+t];
    #pragma unroll
    for (int w=0;w<4;w++) mx = fmaxf(mx, v[i][w]);
  }
  #pragma unroll
  for (int off=32; off; off>>=1) mx = fmaxf(mx, __shfl_xor(mx, off));
  __shared__ float sr1[4], sr2[4];
  if (lane==0) sr1[wid]=mx;
  __syncthreads();
  mx = fmaxf(fmaxf(sr1[0],sr1[1]), fmaxf(sr1[2],sr1[3]));
  float sum=0.f;
  #pragma unroll
  for (int i=0;i<4;i++)
    #pragma unroll
    for (int w=0;w<4;w++){ float e = expf(v[i][w]-mx); v[i][w]=e; sum+=e; }
  #pragma unroll
  for (int off=32; off; off>>=1) sum += __shfl_xor(sum, off);
  if (lane==0) sr2[wid]=sum;
  __syncthreads();
  sum = sr2[0]+sr2[1]+sr2[2]+sr2[3];
  float invs = 1.0f/sum;
  f32x4* Ab = (f32x4*)(A + (size_t)b*4096);
  #pragma unroll
  for (int i=0;i<4;i++){
    f32x4 a;
    #pragma unroll
    for (int w=0;w<4;w++) a[w] = v[i][w]*invs;
    Ab[i*256+t] = a;
  }
}

// ---------------- K5: fused gate/value GEMM + V + proj GEMM ----------------
// Grid 16 x 128 (XCD-swizzled), 512 threads (8 waves), 32-position tiles.
// LDS: Xl 16KB + Vl 16KB; epilogue reuses 33792B (stride-33 pad). ~3 blocks/CU.
// W fragments loaded DIRECTLY from global (L2-resident).
__global__ __launch_bounds__(512) void k_fused(
    const unsigned short* __restrict__ Ap, const unsigned short* __restrict__ Wc,
    const unsigned short* __restrict__ Wpp, const float* __restrict__ biases,
    const float* __restrict__ A, float* __restrict__ out){
  extern __shared__ unsigned short sm[];
  unsigned short* Xl = sm;            // 8192 elems = 16 KB, [c/8(32)][m(32)][8]
  unsigned short* Vl = sm + 8192;     // 8192 elems = 16 KB, same layout
  int orig = blockIdx.x;
  int wg = (orig&7)*256 + (orig>>3);  // bijective (2048%8==0)
  int b = wg>>7, mt = wg&127;         // 32-position tile index
  int t = threadIdx.x, lane = t&63, w = t>>6;
  size_t tbase = (size_t)(b*32 + (mt>>2))*32768;   // parent 128-tile
  int moff = (mt&3)*32;

  // stage xn tile (linear dest, per-lane src): 1024 units of 16B
  #pragma unroll
  for (int i=0;i<2;i++){
    int u = i*512 + t;
    gload16(Ap + tbase + (size_t)(u>>5)*1024 + (size_t)(moff + (u&31))*8, Xl + (size_t)u*8);
  }
  // A for this tile's 2 position groups (per-lane)
  float A4[2];
  #pragma unroll
  for (int mj=0;mj<2;mj++) A4[mj] = A[(size_t)b*4096 + mt*32 + mj*16 + (lane&15)];
  __syncthreads();

  // ---- GEMM-A: g,v for channels [w*32, w*32+32), all 32 positions ----
  int cw0 = w*32;
  int ntg = cw0>>7, ntv = 2 + (cw0>>7);
  int nbase = (cw0&127);
  f32x4 accg[2][2]={}, accv[2][2]={};
  int k8l = lane>>4;
  #pragma unroll
  for (int kk=0; kk<8; ++kk){
    size_t wrow = ((size_t)(kk>>1)*8 + ((kk&1)<<2) + k8l)*1024;
    short8 wgf[2], wvf[2], xf[2];
    #pragma unroll
    for (int ci=0;ci<2;ci++){
      int n = nbase + ci*16 + (lane&15);
      wgf[ci] = *(const short8*)(Wc + (size_t)ntg*32768 + wrow + (size_t)n*8);
      wvf[ci] = *(const short8*)(Wc + (size_t)ntv*32768 + wrow + (size_t)n*8);
    }
    #pragma unroll
    for (int mj=0;mj<2;mj++)
      xf[mj] = *(const short8*)&Xl[((size_t)(kk*4 + k8l)*32 + mj*16 + (lane&15))*8];
    #pragma unroll
    for (int ci=0;ci<2;ci++)
      #pragma unroll
      for (int mj=0;mj<2;mj++){
        accg[ci][mj] = __builtin_amdgcn_mfma_f32_16x16x32_bf16(wgf[ci], xf[mj], accg[ci][mj],0,0,0);
        accv[ci][mj] = __builtin_amdgcn_mfma_f32_16x16x32_bf16(wvf[ci], xf[mj], accv[ci][mj],0,0,0);
      }
  }

  // ---- V = A*(g+bg)*(v+bv) + xn, write to Vl ----
  #pragma unroll
  for (int ci=0;ci<2;ci++){
    int ch0 = cw0 + ci*16 + ((lane>>4)<<2);   // 4 consecutive channels
    f32x4 bg = *(const f32x4*)&biases[ch0];
    f32x4 bv = *(const f32x4*)&biases[256+ch0];
    #pragma unroll
    for (int mj=0;mj<2;mj++){
      int p = mj*16 + (lane&15);
      const unsigned short* xs = &Xl[((size_t)(ch0>>3)*32 + p)*8 + (ch0&7)];
      uint2v xp_ = *(const uint2v*)xs;
      f32x4 pg = accg[ci][mj] + bg;
      f32x4 pv = accv[ci][mj] + bv;
      float r0 = A4[mj]*pg[0]*pv[0] + bf2f((unsigned short)(xp_[0]&0xffff));
      float r1 = A4[mj]*pg[1]*pv[1] + bf2f((unsigned short)(xp_[0]>>16));
      float r2 = A4[mj]*pg[2]*pv[2] + bf2f((unsigned short)(xp_[1]&0xffff));
      float r3 = A4[mj]*pg[3]*pv[3] + bf2f((unsigned short)(xp_[1]>>16));
      uint2v ov; ov[0] = pk2bf(r0,r1); ov[1] = pk2bf(r2,r3);
      *(uint2v*)&Vl[((size_t)(ch0>>3)*32 + p)*8 + (ch0&7)] = ov;
    }
  }
  __syncthreads();

  // ---- GEMM-B: out[o][p] = Wp @ V, wave owns o in [w*32, w*32+32) ----
  int ow0 = w*32;
  int oh = ow0>>7, obase = (ow0&127);
  f32x4 acco[2][2]={};
  #pragma unroll
  for (int kk=0; kk<8; ++kk){
    size_t wrow = ((size_t)(oh*4 + (kk>>1))*8 + ((kk&1)<<2) + k8l)*1024;
    short8 wpf[2], vf[2];
    #pragma unroll
    for (int oi=0;oi<2;oi++){
      int o = obase + oi*16 + (lane&15);
      wpf[oi] = *(const short8*)(Wpp + wrow + (size_t)o*8);
    }
    #pragma unroll
    for (int mj=0;mj<2;mj++)
      vf[mj] = *(const short8*)&Vl[((size_t)(kk*4 + k8l)*32 + mj*16 + (lane&15))*8];
    #pragma unroll
    for (int oi=0;oi<2;oi++)
      #pragma unroll
      for (int mj=0;mj<2;mj++)
        acco[oi][mj] = __builtin_amdgcn_mfma_f32_16x16x32_bf16(wpf[oi], vf[mj], acco[oi][mj],0,0,0);
  }
  __syncthreads();   // all waves done with Vl/Xl before reuse as fl

  // ---- epilogue: per-wave transpose (stride-33 pad) -> coalesced out ----
  float* fl = (float*)sm + (size_t)w*1056;   // 32 pos x 33
  #pragma unroll
  for (int oi=0;oi<2;oi++)
    #pragma unroll
    for (int mj=0;mj<2;mj++){
      int ol = oi*16 + ((lane>>4)<<2);
      int pl = mj*16 + (lane&15);
      #pragma unroll
      for (int k=0;k<4;k++) fl[(size_t)pl*33 + ol + k] = acco[oi][mj][k];
    }
  asm volatile("s_waitcnt lgkmcnt(0)" ::: "memory");
  #pragma unroll
  for (int rep=0; rep<4; ++rep){
    int ol = rep*8 + (lane>>3);
    int p0 = (lane&7)*4;
    float bo = biases[640 + ow0 + ol];
    f32x4 vo;
    #pragma unroll
    for (int k=0;k<4;k++) vo[k] = fl[(size_t)(p0+k)*33 + ol] + bo;
    *(f32x4*)&out[((size_t)(b*256 + ow0 + ol))*4096 + mt*32 + p0] = vo;
  }
}

// ---------------- launch ----------------
extern "C" void kernel_launch(void* const* d_in, const int* in_sizes, int n_in,
                              void* d_out, int out_size, void* d_ws, size_t ws_size,
                              hipStream_t stream){
  const float* x  = (const float*)d_in[0];
  const float* gW = (const float*)d_in[1];
  const float* gB = (const float*)d_in[2];
  const float* vW = (const float*)d_in[3];
  const float* vB = (const float*)d_in[4];
  const float* zW = (const float*)d_in[5];
  const float* zB = (const float*)d_in[6];
  const float* gm = (const float*)d_in[7];
  const float* bt = (const float*)d_in[8];
  const float* pW = (const float*)d_in[9];
  const float* pB = (const float*)d_in[10];

  char* ws = (char*)d_ws;
  float* stats           = (float*)(ws + 0);                  //  32 KB
  float* biases          = (float*)(ws + 32768);              //  3.5 KB
  float* sim             = (float*)(ws + 40960);              // 256 KB
  unsigned short* wcat   = (unsigned short*)(ws + 303104);    // 320 KB bf16
  unsigned short* proj   = (unsigned short*)(ws + 958464);    // 128 KB bf16
  unsigned short* apack  = (unsigned short*)(ws + 2097152);   // 33.5 MB bf16 (xn) -> 35.7 MB total

  float* out = (float*)d_out;
  float* A   = out + 16777216;  // final A slot (16x64x64 fp32)

  hipLaunchKernelGGL(k_pack_w,  dim3(112),  dim3(256), 0, stream, gW, vW, zW, pW, gB, vB, zB, pB, wcat, proj, biases);
  hipLaunchKernelGGL(k_stats,   dim3(4096), dim3(256), 0, stream, x, stats);
  hipLaunchKernelGGL(k_xn_pack, dim3(8192), dim3(256), 0, stream, x, stats, apack);
  hipLaunchKernelGGL(k_zsim,    dim3(512),  dim3(256), 0, stream, apack, wcat, biases, gm, bt, sim);
  hipLaunchKernelGGL(k_softmax, dim3(16),   dim3(256), 0, stream, sim, A);
  hipLaunchKernelGGL(k_fused,   dim3(2048), dim3(512), 33792, stream, apack, wcat, proj, biases, A, out);
  (void)in_sizes; (void)n_in; (void)out_size; (void)ws_size;
}

// Round 22
// 85.547 us; speedup vs baseline: 1.0166x; 1.0166x over previous
//
#include <hip/hip_runtime.h>
#include <hip/hip_bf16.h>
#include <cstdint>
#include <cstddef>

// GAU fused pipeline. fp32 I/O; bf16 MFMA internally.
// B=16 C=256 H=W=64 (HW=4096) S=128 O=256. ws: 36 MiB.
// RoPE eliminated algebraically (same-position q.k is rotation-invariant).
// Final configuration (best measured, r20): k_zsim counted-vmcnt; k_fused =
// gate/value GEMM + V + proj GEMM in one kernel, 64-pos tiles, W direct from L2.

typedef __attribute__((ext_vector_type(8))) short short8;     // 8 bf16 MFMA frag
typedef __attribute__((ext_vector_type(4))) float f32x4;
typedef __attribute__((ext_vector_type(4))) unsigned int uint4v;
typedef __attribute__((ext_vector_type(2))) unsigned int uint2v;

#define DI __device__ __forceinline__

DI float bf2f(unsigned short u){ unsigned int i = ((unsigned int)u)<<16; float f; __builtin_memcpy(&f,&i,4); return f; }
DI unsigned int pk2bf(float lo, float hi){
  float2 f2; f2.x = lo; f2.y = hi;
  __hip_bfloat162 h = __float22bfloat162_rn(f2);
  unsigned int u; __builtin_memcpy(&u, &h, 4); return u;
}

DI void gload16(const void* g, void* l){
  __builtin_amdgcn_global_load_lds((const __attribute__((address_space(1))) void*)g,
                                   (__attribute__((address_space(3))) void*)l, 16, 0, 0);
}

// ---------------- K0: pack weights fp32->bf16 + biases ----------------
// wcat: [nt(5)][ks(4)][k8(8)][n(128)][8]  (o=nt*128+n, c=ks*64+k8*8+j; nt 0-1 gate, 2-3 value, 4 z)
// proj: [oh(2)][ks(4)][k8(8)][o(128)][8]
__global__ __launch_bounds__(256) void k_pack_w(
    const float* __restrict__ gW, const float* __restrict__ vW,
    const float* __restrict__ zW, const float* __restrict__ pW,
    const float* __restrict__ gB, const float* __restrict__ vB,
    const float* __restrict__ zB, const float* __restrict__ pB,
    unsigned short* __restrict__ wcat, unsigned short* __restrict__ proj,
    float* __restrict__ biases){
  int id = blockIdx.x*256 + threadIdx.x;
  if (id < 20480){
    int n=id&127, k8=(id>>7)&7, ks=(id>>10)&3, nt=id>>12;
    int o = nt*128+n, c0 = ks*64+k8*8;
    const float* src = (o<256) ? gW + (size_t)o*256 + c0
                      : (o<512) ? vW + (size_t)(o-256)*256 + c0
                      :           zW + (size_t)(o-512)*256 + c0;
    f32x4 a = *(const f32x4*)src, b = *(const f32x4*)(src+4);
    uint4v ov;
    ov[0] = pk2bf(a[0],a[1]); ov[1] = pk2bf(a[2],a[3]);
    ov[2] = pk2bf(b[0],b[1]); ov[3] = pk2bf(b[2],b[3]);
    *(uint4v*)(wcat + (size_t)id*8) = ov;
  } else if (id < 28672){
    int q = id - 20480;
    int m=q&127, k8=(q>>7)&7, ks=(q>>10)&3, mt=q>>12;
    int o = mt*128+m, c0 = ks*64+k8*8;
    const float* src = pW + (size_t)o*256 + c0;
    f32x4 a = *(const f32x4*)src, b = *(const f32x4*)(src+4);
    uint4v ov;
    ov[0] = pk2bf(a[0],a[1]); ov[1] = pk2bf(a[2],a[3]);
    ov[2] = pk2bf(b[0],b[1]); ov[3] = pk2bf(b[2],b[3]);
    *(uint4v*)(proj + (size_t)q*8) = ov;
  }
  if (id < 640) biases[id] = id<256 ? gB[id] : id<512 ? vB[id-256] : zB[id-512];
  if (id < 256) biases[640+id] = pB[id];
}

// ---------------- K1: per-(b,c) mean / rstd over 4096 ----------------
__global__ __launch_bounds__(256) void k_stats(const float* __restrict__ x, float* __restrict__ stats){
  int bc = blockIdx.x, t = threadIdx.x, lane = t&63, wid = t>>6;
  const f32x4* row = (const f32x4*)(x + (size_t)bc*4096);
  float s=0.f, q=0.f;
  #pragma unroll
  for (int i=0;i<4;i++){
    f32x4 v = row[i*256+t];
    #pragma unroll
    for (int w=0;w<4;w++){ s += v[w]; q += v[w]*v[w]; }
  }
  #pragma unroll
  for (int off=32; off; off>>=1){ s += __shfl_xor(s,off); q += __shfl_xor(q,off); }
  __shared__ float r1[4], r2[4];
  if (lane==0){ r1[wid]=s; r2[wid]=q; }
  __syncthreads();
  if (t==0){
    float S=r1[0]+r1[1]+r1[2]+r1[3], Q=r2[0]+r2[1]+r2[2]+r2[3];
    float mu = S*(1.0f/4096.0f);
    float var = Q*(1.0f/4096.0f) - mu*mu;
    stats[bc*2]   = mu;
    stats[bc*2+1] = rsqrtf(var + 1e-5f);
  }
}

// ---------------- K2: normalize + pack xn (bf16) ----------------
// apack: [b(16)][mt(32)][ks(4)][k8(8)][m(128)][8], elem = xn[b][c=ks*64+k8*8+j][hw=mt*128+m]
__global__ __launch_bounds__(256) void k_xn_pack(const float* __restrict__ x,
    const float* __restrict__ stats, unsigned short* __restrict__ apack){
  size_t id = (size_t)blockIdx.x*256 + threadIdx.x;
  int m=(int)(id&127), k8=(int)(id>>7)&7, ks=(int)(id>>10)&3, mt=(int)(id>>12)&31, b=(int)(id>>17);
  int hw = mt*128+m, c0 = ks*64+k8*8;
  const float* xp = x + ((size_t)(b*256 + c0))*4096 + hw;
  const float* st = stats + (size_t)(b*256+c0)*2;
  uint4v o;
  #pragma unroll
  for (int j=0;j<8;j+=2){
    float v0 = (xp[(size_t)j*4096]     - st[j*2])   * st[j*2+1];
    float v1 = (xp[(size_t)(j+1)*4096] - st[j*2+2]) * st[j*2+3];
    o[j>>1] = pk2bf(v0, v1);
  }
  *(uint4v*)(apack + id*8) = o;
}

// ---------------- K3: z GEMM + fused affine + same-position q.k -> sim ----------------
// Grid 16 x 32 (XCD-swizzled). BK=32, 3 LDS buffers, depth-2 counted vmcnt.
__global__ __launch_bounds__(256,3) void k_zsim(
    const unsigned short* __restrict__ Ap, const unsigned short* __restrict__ Wc,
    const float* __restrict__ biases, const float* __restrict__ gm, const float* __restrict__ bt,
    float* __restrict__ sim){
  __shared__ alignas(16) unsigned short lds[3][2][4096];
  __shared__ float red[2][4][16][2];
  int orig = blockIdx.x;
  int wg = (orig&7)*64 + (orig>>3);            // bijective (512%8==0)
  int b = wg>>5, mt = wg&31;
  const unsigned short* Xt = Ap + (size_t)(b*32+mt)*32768;
  int t = threadIdx.x, lane = t&63;
  int wo = (t>>6)>>1, wm = (t>>6)&1;

  #define STAGEZ(B, cc) do{ \
    _Pragma("unroll") \
    for (int i_=0;i_<2;i_++){ \
      int u_ = i_*256 + t; \
      int k8_ = u_>>7, slot_ = u_&127; \
      gload16(Wc + ((size_t)(16+((cc)>>1))*8 + (((cc)&1)<<2) + k8_)*1024 + (size_t)slot_*8, &lds[B][0][(size_t)u_*8]); \
      gload16(Xt + ((size_t)((cc)*4 + k8_))*1024 + (size_t)slot_*8, &lds[B][1][(size_t)u_*8]); \
    } \
  }while(0)

  f32x4 accg[2][4]={}, accv[2][4]={};

  #define CZ(B) do{ \
    int k8l_ = lane>>4; \
    short8 wgf_[2], wvf_[2], xf_[4]; \
    _Pragma("unroll") for (int ci_=0;ci_<2;ci_++){ \
      int sg_ = wo*32 + ci_*16 + (lane&15); \
      wgf_[ci_] = *(const short8*)&lds[B][0][(size_t)(k8l_*128 + sg_)*8]; \
      wvf_[ci_] = *(const short8*)&lds[B][0][(size_t)(k8l_*128 + 64 + sg_)*8]; } \
    _Pragma("unroll") for (int mj_=0;mj_<4;mj_++) \
      xf_[mj_] = *(const short8*)&lds[B][1][(size_t)(k8l_*128 + wm*64 + mj_*16 + (lane&15))*8]; \
    _Pragma("unroll") for (int ci_=0;ci_<2;ci_++) \
      _Pragma("unroll") for (int mj_=0;mj_<4;mj_++){ \
        accg[ci_][mj_] = __builtin_amdgcn_mfma_f32_16x16x32_bf16(wgf_[ci_], xf_[mj_], accg[ci_][mj_],0,0,0); \
        accv[ci_][mj_] = __builtin_amdgcn_mfma_f32_16x16x32_bf16(wvf_[ci_], xf_[mj_], accv[ci_][mj_],0,0,0); } \
  }while(0)

  STAGEZ(0,0);
  STAGEZ(1,1);
  asm volatile("s_waitcnt vmcnt(4)" ::: "memory");
  __builtin_amdgcn_s_barrier();
  __builtin_amdgcn_sched_barrier(0);
  #pragma unroll
  for (int c=0; c<8; ++c){
    if (c<6) STAGEZ((c+2)%3, c+2);
    CZ(c%3);
    if (c<6)       asm volatile("s_waitcnt vmcnt(4)" ::: "memory");
    else if (c==6) asm volatile("s_waitcnt vmcnt(0)" ::: "memory");
    if (c<7){ __builtin_amdgcn_s_barrier(); __builtin_amdgcn_sched_barrier(0); }
  }

  float part[4] = {0.f,0.f,0.f,0.f};
  #pragma unroll
  for (int ci=0;ci<2;ci++){
    int cq = wo*32 + ci*16 + ((lane>>4)<<2);
    f32x4 bz0 = *(const f32x4*)&biases[512+cq];
    f32x4 bz1 = *(const f32x4*)&biases[512+64+cq];
    f32x4 g0a = *(const f32x4*)&gm[cq],      g1a = *(const f32x4*)&gm[128+cq];
    f32x4 b0a = *(const f32x4*)&bt[cq],      b1a = *(const f32x4*)&bt[128+cq];
    f32x4 g0b = *(const f32x4*)&gm[64+cq],   g1b = *(const f32x4*)&gm[192+cq];
    f32x4 b0b = *(const f32x4*)&bt[64+cq],   b1b = *(const f32x4*)&bt[192+cq];
    #pragma unroll
    for (int mj=0;mj<4;mj++){
      f32x4 z0 = accg[ci][mj] + bz0;
      f32x4 z1 = accv[ci][mj] + bz1;
      f32x4 c0 = (z0*g0a + b0a) * (z0*g1a + b1a);
      f32x4 c1 = (z1*g0b + b0b) * (z1*g1b + b1b);
      part[mj] += c0[0]+c0[1]+c0[2]+c0[3] + c1[0]+c1[1]+c1[2]+c1[3];
    }
  }
  #pragma unroll
  for (int mj=0;mj<4;mj++){
    float rr = part[mj];
    rr += __shfl_xor(rr, 16);
    rr += __shfl_xor(rr, 32);
    if (lane < 16) red[wm][mj][lane][wo] = rr;
  }
  __syncthreads();
  if (t < 128){
    int wmq = t>>6, mjq = (t>>4)&3, lq = t&15;
    float s = red[wmq][mjq][lq][0] + red[wmq][mjq][lq][1];
    sim[(size_t)b*4096 + mt*128 + wmq*64 + mjq*16 + lq] = s * 0.08838834764831845f;
  }
  #undef STAGEZ
  #undef CZ
}

// ---------------- K4: per-batch softmax over 4096 -> A ----------------
__global__ __launch_bounds__(256) void k_softmax(const float* __restrict__ sim, float* __restrict__ A){
  int b = blockIdx.x, t = threadIdx.x, lane = t&63, wid = t>>6;
  const f32x4* s4 = (const f32x4*)(sim + (size_t)b*4096);
  f32x4 v[4];
  float mx = -3.4e38f;
  #pragma unroll
  for (int i=0;i<4;i++){
    v[i] = s4[i*256+t];
    #pragma unroll
    for (int w=0;w<4;w++) mx = fmaxf(mx, v[i][w]);
  }
  #pragma unroll
  for (int off=32; off; off>>=1) mx = fmaxf(mx, __shfl_xor(mx, off));
  __shared__ float sr1[4], sr2[4];
  if (lane==0) sr1[wid]=mx;
  __syncthreads();
  mx = fmaxf(fmaxf(sr1[0],sr1[1]), fmaxf(sr1[2],sr1[3]));
  float sum=0.f;
  #pragma unroll
  for (int i=0;i<4;i++)
    #pragma unroll
    for (int w=0;w<4;w++){ float e = expf(v[i][w]-mx); v[i][w]=e; sum+=e; }
  #pragma unroll
  for (int off=32; off; off>>=1) sum += __shfl_xor(sum, off);
  if (lane==0) sr2[wid]=sum;
  __syncthreads();
  sum = sr2[0]+sr2[1]+sr2[2]+sr2[3];
  float invs = 1.0f/sum;
  f32x4* Ab = (f32x4*)(A + (size_t)b*4096);
  #pragma unroll
  for (int i=0;i<4;i++){
    f32x4 a;
    #pragma unroll
    for (int w=0;w<4;w++) a[w] = v[i][w]*invs;
    Ab[i*256+t] = a;
  }
}

// ---------------- K5: fused gate/value GEMM + V + proj GEMM ----------------
// Grid 16 x 64 (XCD-swizzled), 512 threads (8 waves), 64-position tiles.
// LDS: Xl 32KB + Vl 32KB; epilogue reuses as 67584B fl (stride-33 pad).
// W fragments loaded DIRECTLY from global (L2-resident) -> no W barriers.
__global__ __launch_bounds__(512,1) void k_fused(
    const unsigned short* __restrict__ Ap, const unsigned short* __restrict__ Wc,
    const unsigned short* __restrict__ Wpp, const float* __restrict__ biases,
    const float* __restrict__ A, float* __restrict__ out){
  extern __shared__ unsigned short sm[];
  unsigned short* Xl = sm;            // 16384 elems = 32 KB, [c/8(32)][m(64)][8]
  unsigned short* Vl = sm + 16384;    // 16384 elems = 32 KB, same layout
  int orig = blockIdx.x;
  int wg = (orig&7)*128 + (orig>>3);  // bijective (1024%8==0)
  int b = wg>>6, mt = wg&63;
  int t = threadIdx.x, lane = t&63, w = t>>6;
  size_t tbase = (size_t)(b*32 + (mt>>1))*32768;
  int moff = (mt&1)*64;

  // stage xn tile (linear dest, per-lane src)
  #pragma unroll
  for (int i=0;i<4;i++){
    int u = i*512 + t;
    gload16(Ap + tbase + (size_t)(u>>6)*1024 + (size_t)(moff + (u&63))*8, Xl + (size_t)u*8);
  }
  // A for this tile's 4 position groups (per-lane)
  float A4[4];
  #pragma unroll
  for (int mj=0;mj<4;mj++) A4[mj] = A[(size_t)b*4096 + mt*64 + mj*16 + (lane&15)];
  __syncthreads();

  // ---- GEMM-A: g,v for channels [w*32, w*32+32), all 64 positions ----
  int cw0 = w*32;
  int ntg = cw0>>7, ntv = 2 + (cw0>>7);
  int nbase = (cw0&127);
  f32x4 accg[2][4]={}, accv[2][4]={};
  int k8l = lane>>4;
  short8 wgp[2][2], wvp[2][2];   // ping-pong W prefetch

  #define LOADWA(K) do{ \
    size_t wrow_ = ((size_t)((K)>>1)*8 + (((K)&1)<<2) + k8l)*1024; \
    _Pragma("unroll") for (int ci_=0;ci_<2;ci_++){ \
      int n_ = nbase + ci_*16 + (lane&15); \
      wgp[(K)&1][ci_] = *(const short8*)(Wc + (size_t)ntg*32768 + wrow_ + (size_t)n_*8); \
      wvp[(K)&1][ci_] = *(const short8*)(Wc + (size_t)ntv*32768 + wrow_ + (size_t)n_*8); \
    } \
  }while(0)

  LOADWA(0);
  #pragma unroll
  for (int kk=0; kk<8; ++kk){
    if (kk<7) LOADWA(kk+1);
    short8 xf[4];
    #pragma unroll
    for (int mj=0;mj<4;mj++)
      xf[mj] = *(const short8*)&Xl[((size_t)(kk*4 + k8l)*64 + mj*16 + (lane&15))*8];
    #pragma unroll
    for (int ci=0;ci<2;ci++)
      #pragma unroll
      for (int mj=0;mj<4;mj++){
        accg[ci][mj] = __builtin_amdgcn_mfma_f32_16x16x32_bf16(wgp[kk&1][ci], xf[mj], accg[ci][mj],0,0,0);
        accv[ci][mj] = __builtin_amdgcn_mfma_f32_16x16x32_bf16(wvp[kk&1][ci], xf[mj], accv[ci][mj],0,0,0);
      }
  }
  #undef LOADWA

  // ---- preload GEMM-B W frags (latency hidden under V-phase + barrier) ----
  int ow0 = w*32;
  int oh = ow0>>7, obase = (ow0&127);
  short8 wpf[8][2];
  #pragma unroll
  for (int kk=0; kk<8; ++kk){
    size_t wrow = ((size_t)(oh*4 + (kk>>1))*8 + ((kk&1)<<2) + k8l)*1024;
    #pragma unroll
    for (int oi=0;oi<2;oi++){
      int o = obase + oi*16 + (lane&15);
      wpf[kk][oi] = *(const short8*)(Wpp + wrow + (size_t)o*8);
    }
  }

  // ---- V = A*(g+bg)*(v+bv) + xn, write to Vl ----
  #pragma unroll
  for (int ci=0;ci<2;ci++){
    int ch0 = cw0 + ci*16 + ((lane>>4)<<2);   // 4 consecutive channels
    f32x4 bg = *(const f32x4*)&biases[ch0];
    f32x4 bv = *(const f32x4*)&biases[256+ch0];
    #pragma unroll
    for (int mj=0;mj<4;mj++){
      int p = mj*16 + (lane&15);
      const unsigned short* xs = &Xl[((size_t)(ch0>>3)*64 + p)*8 + (ch0&7)];
      uint2v xp_ = *(const uint2v*)xs;
      f32x4 pg = accg[ci][mj] + bg;
      f32x4 pv = accv[ci][mj] + bv;
      float r0 = A4[mj]*pg[0]*pv[0] + bf2f((unsigned short)(xp_[0]&0xffff));
      float r1 = A4[mj]*pg[1]*pv[1] + bf2f((unsigned short)(xp_[0]>>16));
      float r2 = A4[mj]*pg[2]*pv[2] + bf2f((unsigned short)(xp_[1]&0xffff));
      float r3 = A4[mj]*pg[3]*pv[3] + bf2f((unsigned short)(xp_[1]>>16));
      uint2v ov; ov[0] = pk2bf(r0,r1); ov[1] = pk2bf(r2,r3);
      *(uint2v*)&Vl[((size_t)(ch0>>3)*64 + p)*8 + (ch0&7)] = ov;
    }
  }
  __syncthreads();

  // ---- GEMM-B: out[o][p] = Wp @ V ----
  f32x4 acco[2][4]={};
  #pragma unroll
  for (int kk=0; kk<8; ++kk){
    short8 vf[4];
    #pragma unroll
    for (int mj=0;mj<4;mj++)
      vf[mj] = *(const short8*)&Vl[((size_t)(kk*4 + k8l)*64 + mj*16 + (lane&15))*8];
    #pragma unroll
    for (int oi=0;oi<2;oi++)
      #pragma unroll
      for (int mj=0;mj<4;mj++)
        acco[oi][mj] = __builtin_amdgcn_mfma_f32_16x16x32_bf16(wpf[kk][oi], vf[mj], acco[oi][mj],0,0,0);
  }
  __syncthreads();   // all waves done with Vl/Xl before reuse as fl

  // ---- epilogue: per-wave transpose (stride-33 pad) -> coalesced out ----
  float* fl = (float*)sm + (size_t)w*2112;   // 64 pos x 33
  #pragma unroll
  for (int oi=0;oi<2;oi++)
    #pragma unroll
    for (int mj=0;mj<4;mj++){
      int ol = oi*16 + ((lane>>4)<<2);
      int pl = mj*16 + (lane&15);
      #pragma unroll
      for (int k=0;k<4;k++) fl[(size_t)pl*33 + ol + k] = acco[oi][mj][k];
    }
  asm volatile("s_waitcnt lgkmcnt(0)" ::: "memory");
  #pragma unroll
  for (int rep=0; rep<8; ++rep){
    int ol = rep*4 + (lane>>4);
    int p0 = (lane&15)*4;
    float bo = biases[640 + ow0 + ol];
    f32x4 vo;
    #pragma unroll
    for (int k=0;k<4;k++) vo[k] = fl[(size_t)(p0+k)*33 + ol] + bo;
    *(f32x4*)&out[((size_t)(b*256 + ow0 + ol))*4096 + mt*64 + p0] = vo;
  }
}

// ---------------- launch ----------------
extern "C" void kernel_launch(void* const* d_in, const int* in_sizes, int n_in,
                              void* d_out, int out_size, void* d_ws, size_t ws_size,
                              hipStream_t stream){
  const float* x  = (const float*)d_in[0];
  const float* gW = (const float*)d_in[1];
  const float* gB = (const float*)d_in[2];
  const float* vW = (const float*)d_in[3];
  const float* vB = (const float*)d_in[4];
  const float* zW = (const float*)d_in[5];
  const float* zB = (const float*)d_in[6];
  const float* gm = (const float*)d_in[7];
  const float* bt = (const float*)d_in[8];
  const float* pW = (const float*)d_in[9];
  const float* pB = (const float*)d_in[10];

  char* ws = (char*)d_ws;
  float* stats           = (float*)(ws + 0);                  //  32 KB
  float* biases          = (float*)(ws + 32768);              //  3.5 KB
  float* sim             = (float*)(ws + 40960);              // 256 KB
  unsigned short* wcat   = (unsigned short*)(ws + 303104);    // 320 KB bf16
  unsigned short* proj   = (unsigned short*)(ws + 958464);    // 128 KB bf16
  unsigned short* apack  = (unsigned short*)(ws + 2097152);   // 33.5 MB bf16 (xn) -> 35.7 MB total

  float* out = (float*)d_out;
  float* A   = out + 16777216;  // final A slot (16x64x64 fp32)

  hipLaunchKernelGGL(k_pack_w,  dim3(112),  dim3(256), 0, stream, gW, vW, zW, pW, gB, vB, zB, pB, wcat, proj, biases);
  hipLaunchKernelGGL(k_stats,   dim3(4096), dim3(256), 0, stream, x, stats);
  hipLaunchKernelGGL(k_xn_pack, dim3(8192), dim3(256), 0, stream, x, stats, apack);
  hipLaunchKernelGGL(k_zsim,    dim3(512),  dim3(256), 0, stream, apack, wcat, biases, gm, bt, sim);
  hipLaunchKernelGGL(k_softmax, dim3(16),   dim3(256), 0, stream, sim, A);
  hipLaunchKernelGGL(k_fused,   dim3(1024), dim3(512), 67584, stream, apack, wcat, proj, biases, A, out);
  (void)in_sizes; (void)n_in; (void)out_size; (void)ws_size;
}